// Round 9
// baseline (285.295 us; speedup 1.0000x reference)
//
#include <hip/hip_runtime.h>
#include <math.h>

#define ALPHA 0.2f
#define BN_EPS 1e-5f

typedef __attribute__((ext_vector_type(8))) short short8;
typedef __attribute__((ext_vector_type(4))) float v4f;

// ---- bf16 bit helpers (RNE) ----
__device__ __forceinline__ unsigned short f2bf_rne(float f) {
    union { float f; unsigned u; } x; x.f = f;
    unsigned r = x.u + 0x7FFFu + ((x.u >> 16) & 1u);
    return (unsigned short)(r >> 16);
}
__device__ __forceinline__ float bf2f(unsigned short h) {
    union { float f; unsigned u; } x; x.u = ((unsigned)h) << 16;
    return x.f;
}
// packed f32x2 -> bf16x2 (a0 -> low16). Rounding mode of HW cvt_pk is
// irrelevant for hi/lo pairs: lo is computed against the actual hi.
__device__ __forceinline__ unsigned cvtpk_bf16(float a0, float a1) {
    unsigned r;
    asm("v_cvt_pk_bf16_f32 %0, %1, %2" : "=v"(r) : "v"(a0), "v"(a1));
    return r;
}
__device__ __forceinline__ void hilo_pair(float a0, float a1, unsigned& hp, unsigned& lp) {
    hp = cvtpk_bf16(a0, a1);
    union { unsigned u; float f; } c0, c1;
    c0.u = hp << 16; c1.u = hp & 0xFFFF0000u;
    lp = cvtpk_bf16(a0 - c0.f, a1 - c1.f);
}

// ======== prep kernel: pack conv1 + conv2 weights as MFMA B-fragments ========
// conv1 (kw-split, 11 GEMMs of K=25 pad 32 over k=ic*5+kh): slot
//   s = (kw*2+nt)*64+lane, elem j <-> B_kw[k=(lane>>4)*8+j][oc=nt*16+(lane&15)]
//   = w1[oc*275 + k*11 + kw], zero for k>=25.
//   hi at ws16[0..11264), lo at ws16[11264..22528).
// conv2 (kw-split, 5 GEMMs of K=32=ic): slot s2 = ((kw*2+nt)*64+lane):
//   elem j <-> B_kw[ic=(lane>>4)*8+j][oc=nt*16+(lane&15)] = w2[oc][ic][kw].
//   hi at ws16[22528..27648), lo at ws16[27648..32768).  Total 64 KB.
__global__ __launch_bounds__(256) void prep_kernel(const float* __restrict__ w1,
                                                   const float* __restrict__ w2,
                                                   unsigned short* __restrict__ ws16) {
    int s = blockIdx.x * 256 + threadIdx.x;
    if (s < 1408) {
        int lane = s & 63;
        int ktnt = s >> 6;           // 0..21 = kw*2+nt
        int kw = ktnt >> 1;
        int nt = ktnt & 1;
        int oc = nt * 16 + (lane & 15);
        int quad = lane >> 4;
        for (int j = 0; j < 8; ++j) {
            int k = quad * 8 + j;    // ic*5+kh, pad >=25 zero
            float w = (k < 25) ? w1[oc * 275 + k * 11 + kw] : 0.f;
            unsigned short h = f2bf_rne(w);
            ws16[s * 8 + j] = h;
            ws16[11264 + s * 8 + j] = f2bf_rne(w - bf2f(h));
        }
    } else if (s < 2048) {
        int s2 = s - 1408;
        int lane = s2 & 63;
        int ktnt = s2 >> 6;          // 0..9 = kw*2+nt
        int kw = ktnt >> 1;
        int nt = ktnt & 1;
        int oc = nt * 16 + (lane & 15);
        int quad = lane >> 4;
        for (int j = 0; j < 8; ++j) {
            int ic = quad * 8 + j;
            float w = w2[oc * 160 + ic * 5 + kw];
            unsigned short h = f2bf_rne(w);
            ws16[22528 + s2 * 8 + j] = h;
            ws16[27648 + s2 * 8 + j] = f2bf_rne(w - bf2f(h));
        }
    }
}

// ======== main kernel ========
// Per-item LDS map (dwords, stride IT=2264), regions overlap by lifetime:
//  [0,858)    : hbf-HI (dw kd*66+ch, kd=pos>>1 0..12)  ph1epi..ph4+5-reads;
//               pt [0,832)  ph4+5epi..ph6-reads (barrier inside ph4+5);
//               h2bf hi [0,396)+lo [396,792)  ph6epi..ph9+10-reads (barrier in ph6);
//               p2f f32 [0,384)  ph9+10epi..ph11 (barrier inside ph9+10)
//  [858,1716) : hbf-LO  ph1epi..ph2-MFMA-reads only (barrier inside ph2)
//  [858,1946) : attb bf16 att B-frags, HI ONLY (att-lo term dropped; see ph4+5
//               note): dw half*544 + md*34 + n (md=m>>1 0..15, n 0..31).
//               layer1: ph2epi..ph4+5-reads; layer2: ph7epi..ph9+10-reads
//  [860,2260) : xkT bf16 x^T pair-packed halo'd: [half][w'=0..34][20dw rows]
//               ph0..ph1-MFMAs (barrier inside ph1 before hbf epi)
// cst @4528 [4][32]. Total 4656 dw = 18624 B -> 8 blocks/CU (32 waves, max occ).
#define IT 2264
#define HLO 858
#define XKT 860
#define CSTO 4528
#define LDS_TOTAL (4528 + 128)

__global__ __launch_bounds__(256, 8) void gcn_kernel(
    const float* __restrict__ x,
    const float* __restrict__ w1, const float* __restrict__ b1,
    const float* __restrict__ g1, const float* __restrict__ be1,
    const float* __restrict__ mu1, const float* __restrict__ va1,
    const float* __restrict__ w2, const float* __restrict__ b2,
    const float* __restrict__ g2, const float* __restrict__ be2,
    const float* __restrict__ mu2, const float* __restrict__ va2,
    const float* __restrict__ lw, const float* __restrict__ lb,
    const unsigned short* __restrict__ ws16,
    float* __restrict__ out)
{
    __shared__ __align__(16) float lds[LDS_TOTAL];
    float* cst = lds + CSTO;

    const int tid = threadIdx.x;
    const int b0  = blockIdx.x * 2;

    // ---- phase 0: row-based load -> xkT (bf16, transposed, pair-packed, halo) ----
    // xkT row w' holds x[w=(w'-5) mod 25] at us slot k=ic*5+kh; row stride 40 us.
    // main w'=w+5; left halo w'=w-20 (w>=20); right halo w'=w+30 (w<=4).
    if (tid < 250) {
        int rowid = tid / 5;             // (it, k): 50 source rows of 50 floats
        int s = tid - rowid * 5;         // fifth-of-row: w50 in [s*10, s*10+10)
        int it = (rowid >= 25) ? 1 : 0;
        int k = rowid - it * 25;
        const float2* src = (const float2*)(x + (size_t)b0 * 1250) + it * 625 + k * 25 + s * 5;
        unsigned short* XU = (unsigned short*)(lds + it * IT + XKT);
#pragma unroll
        for (int e = 0; e < 5; ++e) {
            float2 v = src[e];
            int w50 = s * 10 + 2 * e;
            {
                int half = (w50 >= 25) ? 1 : 0;
                int w = w50 - half * 25;
                unsigned short u = f2bf_rne(v.x);
                int a = half * 1400 + (w + 5) * 40 + k;
                XU[a] = u;
                if (w >= 20) XU[a - 1000] = u;
                if (w <= 4)  XU[a + 1000] = u;
            }
            {
                int w51 = w50 + 1;
                int half = (w51 >= 25) ? 1 : 0;
                int w = w51 - half * 25;
                unsigned short u = f2bf_rne(v.y);
                int a = half * 1400 + (w + 5) * 40 + k;
                XU[a] = u;
                if (w >= 20) XU[a - 1000] = u;
                if (w <= 4)  XU[a + 1000] = u;
            }
        }
    }
    // zero pads: k=25 ushort + kd 13..15 dwords, all 140 (it,half,w') rows
    if (tid < 140) {
        int it = (tid >= 70) ? 1 : 0;
        int r2 = tid - it * 70;
        int half = (r2 >= 35) ? 1 : 0;
        int w3 = r2 - half * 35;
        int a = half * 1400 + w3 * 40;   // even
        unsigned short* XU = (unsigned short*)(lds + it * IT + XKT);
        XU[a + 25] = 0;
        unsigned* XD = (unsigned*)XU;
        XD[(a >> 1) + 13] = 0;
        XD[(a >> 1) + 14] = 0;
        XD[(a >> 1) + 15] = 0;
    }
    if (tid < 64) {
        int oc = tid & 31;
        if (tid < 32) {
            float inv = g1[oc] * rsqrtf(va1[oc] + BN_EPS);
            cst[oc]      = inv;
            cst[32 + oc] = be1[oc] - mu1[oc] * inv;
        } else {
            float inv = g2[oc] * rsqrtf(va2[oc] + BN_EPS);
            cst[64 + oc] = inv;
            cst[96 + oc] = be2[oc] - mu2[oc] * inv;
        }
    }
    __syncthreads();

    // ---- phase 1: conv1 as 11 kw-split MFMA GEMMs (K=25 pad 32), A=1 b128/tile ----
    // M remap: mg = half*32 + pos (junk rows pos>=25 clamp to 24, discarded in epi).
    {
        const int wave = tid >> 6, lane = tid & 63;
        const int it = wave >> 1;
        const int Mtb = (wave & 1) * 2;
        const int quad = lane >> 4, m16 = lane & 15;
        const unsigned* XK = (const unsigned*)(lds + it * IT + XKT);

        int ab[2];
#pragma unroll
        for (int mt = 0; mt < 2; ++mt) {
            int mg = (Mtb + mt) * 16 + m16;
            int half = mg >> 5, pos = mg & 31;
            pos = (pos > 24) ? 24 : pos;
            ab[mt] = half * 700 + pos * 20 + quad * 4;
        }

        v4f zz = {0.f, 0.f, 0.f, 0.f};
        v4f acc[2][2];
        acc[0][0] = zz; acc[0][1] = zz; acc[1][0] = zz; acc[1][1] = zz;

        for (int kw = 0; kw < 11; ++kw) {
            short8 a0 = *(const short8*)(XK + ab[0] + kw * 20);
            short8 a1 = *(const short8*)(XK + ab[1] + kw * 20);
#pragma unroll
            for (int nt = 0; nt < 2; ++nt) {
                const short8* ph = (const short8*)(ws16 + ((kw * 2 + nt) * 64 + lane) * 8);
                const short8* pl = (const short8*)(ws16 + 11264 + ((kw * 2 + nt) * 64 + lane) * 8);
                short8 bh = *ph;
                short8 bl = *pl;
                acc[0][nt] = __builtin_amdgcn_mfma_f32_16x16x32_bf16(a0, bh, acc[0][nt], 0, 0, 0);
                acc[0][nt] = __builtin_amdgcn_mfma_f32_16x16x32_bf16(a0, bl, acc[0][nt], 0, 0, 0);
                acc[1][nt] = __builtin_amdgcn_mfma_f32_16x16x32_bf16(a1, bh, acc[1][nt], 0, 0, 0);
                acc[1][nt] = __builtin_amdgcn_mfma_f32_16x16x32_bf16(a1, bl, acc[1][nt], 0, 0, 0);
            }
        }

        __syncthreads();   // all xkT reads done before hbf-lo epi overwrites [858,1716)

        // epilogue: D rows quad*4+r are mg; in-lane r-pairs = pos-pairs -> one
        // hilo dword per (kd,ch). hi dw kd*66+ch, lo +858. Pair (24,25): odd
        // slot holds junk (finite acc), masked by ph2 / discarded by ph4+5.
        float biasv0 = b1[m16], biasv1 = b1[16 + m16];
        unsigned* HD = (unsigned*)(lds + it * IT);
#pragma unroll
        for (int mt = 0; mt < 2; ++mt) {
#pragma unroll
            for (int rr = 0; rr < 2; ++rr) {
                int mg0 = (Mtb + mt) * 16 + quad * 4 + rr * 2;
                int half = mg0 >> 5, pos0 = mg0 & 31;
                if (pos0 <= 24) {
                    int kd = pos0 >> 1;
#pragma unroll
                    for (int nt = 0; nt < 2; ++nt) {
                        float bias = nt ? biasv1 : biasv0;
                        float v0 = acc[mt][nt][rr * 2] + bias;
                        float v1 = acc[mt][nt][rr * 2 + 1] + bias;
                        unsigned hp, lp;
                        hilo_pair(v0, v1, hp, lp);
                        int ch = half * 32 + nt * 16 + m16;
                        HD[kd * 66 + ch] = hp;
                        HD[858 + kd * 66 + ch] = lp;
                    }
                }
            }
        }
    }
    __syncthreads();

    // ---- phase 2 (fused): layer-1 scores -> leaky -> softmax(in-reg) -> attb ----
    // S[m][n]=<H[m],H[n]> (K=25 pad 32), m=mt*16+q*4+r, n=nt*16+m16.
    // softmax over n = reduce over (nt regs x m16 lanes) via 4-step shfl_xor.
    // attb (HI only): dw HLO + half*544 + md*34 + n (md=m>>1, in-lane r-pairs).
    {
        const int wave = tid >> 6, lane = tid & 63;
        const int it = wave >> 1, half = wave & 1;
        const int m16 = lane & 15, q = lane >> 4;
        const unsigned* D = (const unsigned*)(lds + it * IT);
        short8 fh[2], fl[2];
#pragma unroll
        for (int t = 0; t < 2; ++t) {
            int row = half * 32 + t * 16 + m16;
            union { unsigned u[4]; short8 v; } H, L;
#pragma unroll
            for (int i = 0; i < 4; ++i) {
                int k0 = q * 8 + 2 * i;
                unsigned mh = D[(k0 >> 1) * 66 + row];
                unsigned ml = D[858 + (k0 >> 1) * 66 + row];
                if (k0 == 24) { mh &= 0xFFFFu; ml &= 0xFFFFu; }
                if (k0 > 24)  { mh = 0u; ml = 0u; }
                H.u[i] = mh; L.u[i] = ml;
            }
            fh[t] = H.v; fl[t] = L.v;
        }
        v4f zz = {0.f, 0.f, 0.f, 0.f};
        v4f acc[2][2];
        acc[0][0] = zz; acc[0][1] = zz; acc[1][0] = zz; acc[1][1] = zz;
#pragma unroll
        for (int mt = 0; mt < 2; ++mt)
#pragma unroll
            for (int nt = 0; nt < 2; ++nt) {
                acc[mt][nt] = __builtin_amdgcn_mfma_f32_16x16x32_bf16(fh[mt], fh[nt], acc[mt][nt], 0, 0, 0);
                acc[mt][nt] = __builtin_amdgcn_mfma_f32_16x16x32_bf16(fh[mt], fl[nt], acc[mt][nt], 0, 0, 0);
                acc[mt][nt] = __builtin_amdgcn_mfma_f32_16x16x32_bf16(fl[mt], fh[nt], acc[mt][nt], 0, 0, 0);
            }
        // leaky
#pragma unroll
        for (int mt = 0; mt < 2; ++mt)
#pragma unroll
            for (int nt = 0; nt < 2; ++nt)
#pragma unroll
                for (int r = 0; r < 4; ++r) {
                    float s = acc[mt][nt][r];
                    acc[mt][nt][r] = (s > 0.f) ? s : ALPHA * s;
                }
        // softmax over n (per m = (mt,r)): max + exp + sum + scale
        float invs[2][4];
#pragma unroll
        for (int mt = 0; mt < 2; ++mt)
#pragma unroll
            for (int r = 0; r < 4; ++r) {
                float m2 = fmaxf(acc[mt][0][r], acc[mt][1][r]);
                m2 = fmaxf(m2, __shfl_xor(m2, 1));
                m2 = fmaxf(m2, __shfl_xor(m2, 2));
                m2 = fmaxf(m2, __shfl_xor(m2, 4));
                m2 = fmaxf(m2, __shfl_xor(m2, 8));
                float e0 = __expf(acc[mt][0][r] - m2);
                float e1 = __expf(acc[mt][1][r] - m2);
                acc[mt][0][r] = e0; acc[mt][1][r] = e1;
                float sm = e0 + e1;
                sm += __shfl_xor(sm, 1);
                sm += __shfl_xor(sm, 2);
                sm += __shfl_xor(sm, 4);
                sm += __shfl_xor(sm, 8);
                invs[mt][r] = 1.f / sm;
            }
        __syncthreads();   // all hbf-lo MFMA reads done before attb overwrites
        unsigned* ATB = (unsigned*)(lds + it * IT) + HLO + half * 544;
#pragma unroll
        for (int mt = 0; mt < 2; ++mt)
#pragma unroll
            for (int rr = 0; rr < 2; ++rr) {
                int md = 8 * mt + 2 * q + rr;
#pragma unroll
                for (int nt = 0; nt < 2; ++nt) {
                    float a0 = acc[mt][nt][rr * 2]     * invs[mt][rr * 2];
                    float a1 = acc[mt][nt][rr * 2 + 1] * invs[mt][rr * 2 + 1];
                    ATB[md * 34 + nt * 16 + m16] = cvtpk_bf16(a0, a1);
                }
            }
    }
    __syncthreads();

    // ---- phase 4+5: (att @ h1) via MFMA, D[pos][n] -> bn1 -> pool (in-lane)
    //      -> relu -> pt. A = h1 HI, B = att HI (both lo terms dropped; each is
    //      2^-9-relative, mirrored pair of R5's verified-neutral drop). 1-term.
    {
        const int wave = tid >> 6, lane = tid & 63;
        const int it = wave >> 1, half = wave & 1;
        const int m16 = lane & 15, q = lane >> 4;
        const unsigned short* U = (const unsigned short*)(lds + it * IT);
        const unsigned* ATB = (const unsigned*)(lds + it * IT) + HLO + half * 544;

        // A-frags (hi): A[pos][k=m] = h1[ch=half*32+m][pos]; pos = mt*16 + m16
        short8 ah[2];
#pragma unroll
        for (int mt = 0; mt < 2; ++mt) {
            int pos = mt * 16 + m16;
            int kd = pos >> 1, par = pos & 1;
            union { unsigned u[4]; short8 v; } H;
#pragma unroll
            for (int i = 0; i < 4; ++i) {
                int ch = half * 32 + q * 8 + 2 * i;
                unsigned h0 = U[kd * 132 + ch * 2 + par];
                unsigned h1u = U[kd * 132 + (ch + 1) * 2 + par];
                H.u[i] = h0 | (h1u << 16);
            }
            ah[mt] = H.v;
        }
        // B-frags: attb dwords (md = q*4+i, n = nt*16+m16)
        short8 bh[2];
#pragma unroll
        for (int nt = 0; nt < 2; ++nt) {
            union { unsigned u[4]; short8 v; } H;
#pragma unroll
            for (int i = 0; i < 4; ++i)
                H.u[i] = ATB[(q * 4 + i) * 34 + nt * 16 + m16];
            bh[nt] = H.v;
        }
        v4f zz = {0.f, 0.f, 0.f, 0.f};
        v4f acc[2][2];
        acc[0][0] = zz; acc[0][1] = zz; acc[1][0] = zz; acc[1][1] = zz;
#pragma unroll
        for (int mt = 0; mt < 2; ++mt)
#pragma unroll
            for (int nt = 0; nt < 2; ++nt)
                acc[mt][nt] = __builtin_amdgcn_mfma_f32_16x16x32_bf16(ah[mt], bh[nt], acc[mt][nt], 0, 0, 0);

        __syncthreads();   // all hbf-hi reads done before pt overwrites [0,832)

        // epilogue: pos = mt*16 + q*4 + r (r-pairs pool in-lane); n = nt*16+m16
        unsigned short* PT = (unsigned short*)(lds + it * IT) + half * 832;
#pragma unroll
        for (int mt = 0; mt < 2; ++mt)
#pragma unroll
            for (int nt = 0; nt < 2; ++nt) {
                int n = nt * 16 + m16;
                float inv = cst[n], sh = cst[32 + n];
#pragma unroll
                for (int rr = 0; rr < 2; ++rr) {
                    int pos0 = mt * 16 + q * 4 + rr * 2;
                    if (pos0 < 24) {
                        float v0 = acc[mt][nt][rr * 2] * inv + sh;
                        float v1 = acc[mt][nt][rr * 2 + 1] * inv + sh;
                        float p = fmaxf(fmaxf(v0, v1), 0.f);
                        int j = pos0 >> 1;
                        unsigned short h = f2bf_rne(p);
                        PT[(n >> 1) * 26 + j * 2 + (n & 1)] = h;
                        PT[416 + (n >> 1) * 26 + j * 2 + (n & 1)] = f2bf_rne(p - bf2f(h));
                    }
                }
            }
    }
    __syncthreads();

    // ---- phase 6: conv2 as 5 kw-split MFMA GEMMs (K=32=ic), A from pt ----
    {
        const int wave = tid >> 6, lane = tid & 63;
        const int it = wave >> 1, half = wave & 1;
        const int m16 = lane & 15, q = lane >> 4;
        const unsigned* PTD = (const unsigned*)(lds + it * IT) + half * 416;

        v4f zz = {0.f, 0.f, 0.f, 0.f};
        v4f acc[2]; acc[0] = zz; acc[1] = zz;
#pragma unroll
        for (int kw = 0; kw < 5; ++kw) {
            int owr = m16 + kw - 2;
            if (owr < 0) owr += 12;
            if (owr >= 12) owr -= 12;
            union { unsigned u[4]; short8 v; } H, L;
#pragma unroll
            for (int i = 0; i < 4; ++i) {
                H.u[i] = PTD[(q * 4 + i) * 13 + owr];
                L.u[i] = PTD[208 + (q * 4 + i) * 13 + owr];
            }
#pragma unroll
            for (int nt = 0; nt < 2; ++nt) {
                const short8* ph = (const short8*)(ws16 + 22528 + ((kw * 2 + nt) * 64 + lane) * 8);
                const short8* pl = (const short8*)(ws16 + 27648 + ((kw * 2 + nt) * 64 + lane) * 8);
                short8 wbh = *ph, wbl = *pl;
                acc[nt] = __builtin_amdgcn_mfma_f32_16x16x32_bf16(H.v, wbh, acc[nt], 0, 0, 0);
                acc[nt] = __builtin_amdgcn_mfma_f32_16x16x32_bf16(H.v, wbl, acc[nt], 0, 0, 0);
                acc[nt] = __builtin_amdgcn_mfma_f32_16x16x32_bf16(L.v, wbh, acc[nt], 0, 0, 0);
            }
        }

        __syncthreads();   // all pt reads done before h2bf overwrites [0,792)

        // epilogue: D[ow=q*4+r][oc]; h2bf hi dw kd*66+ch, lo +396 (kd = ow pair)
        if (q < 3) {
            unsigned* H2 = (unsigned*)(lds + it * IT);
#pragma unroll
            for (int nt = 0; nt < 2; ++nt) {
                float bias = b2[nt * 16 + m16];
                int ch = half * 32 + nt * 16 + m16;
#pragma unroll
                for (int rr = 0; rr < 2; ++rr) {
                    float v0 = acc[nt][rr * 2] + bias;
                    float v1 = acc[nt][rr * 2 + 1] + bias;
                    unsigned hp, lp;
                    hilo_pair(v0, v1, hp, lp);
                    H2[(q * 2 + rr) * 66 + ch] = hp;
                    H2[396 + (q * 2 + rr) * 66 + ch] = lp;
                }
            }
        }
    }
    __syncthreads();

    // ---- phase 7 (fused): layer-2 scores -> leaky -> softmax -> attb (HI only) ----
    // S[m][n]=<H2[1-half][m],H2[half][n]>, K=12 pad 32. attb write region
    // [858,1946) disjoint from h2bf reads [0,792) -> no internal barrier.
    {
        const int wave = tid >> 6, lane = tid & 63;
        const int it = wave >> 1, half = wave & 1;
        const int m16 = lane & 15, q = lane >> 4;
        const unsigned* D = (const unsigned*)(lds + it * IT);
        short8 ah[2], al[2], bh[2], bl[2];
#pragma unroll
        for (int t = 0; t < 2; ++t) {
            int rowA = (1 - half) * 32 + t * 16 + m16;
            int rowB = half * 32 + t * 16 + m16;
            union { unsigned u[4]; short8 v; } HA, LA, HB, LB;
#pragma unroll
            for (int i = 0; i < 4; ++i) {
                int k0 = q * 8 + 2 * i;
                unsigned a_h = D[(k0 >> 1) * 66 + rowA];
                unsigned a_l = D[396 + (k0 >> 1) * 66 + rowA];
                unsigned b_h = D[(k0 >> 1) * 66 + rowB];
                unsigned b_l = D[396 + (k0 >> 1) * 66 + rowB];
                if (k0 > 10) { a_h = 0u; a_l = 0u; b_h = 0u; b_l = 0u; }
                HA.u[i] = a_h; LA.u[i] = a_l; HB.u[i] = b_h; LB.u[i] = b_l;
            }
            ah[t] = HA.v; al[t] = LA.v; bh[t] = HB.v; bl[t] = LB.v;
        }
        v4f zz = {0.f, 0.f, 0.f, 0.f};
        v4f acc[2][2];
        acc[0][0] = zz; acc[0][1] = zz; acc[1][0] = zz; acc[1][1] = zz;
#pragma unroll
        for (int mt = 0; mt < 2; ++mt)
#pragma unroll
            for (int nt = 0; nt < 2; ++nt) {
                acc[mt][nt] = __builtin_amdgcn_mfma_f32_16x16x32_bf16(ah[mt], bh[nt], acc[mt][nt], 0, 0, 0);
                acc[mt][nt] = __builtin_amdgcn_mfma_f32_16x16x32_bf16(ah[mt], bl[nt], acc[mt][nt], 0, 0, 0);
                acc[mt][nt] = __builtin_amdgcn_mfma_f32_16x16x32_bf16(al[mt], bh[nt], acc[mt][nt], 0, 0, 0);
            }
        // leaky
#pragma unroll
        for (int mt = 0; mt < 2; ++mt)
#pragma unroll
            for (int nt = 0; nt < 2; ++nt)
#pragma unroll
                for (int r = 0; r < 4; ++r) {
                    float s = acc[mt][nt][r];
                    acc[mt][nt][r] = (s > 0.f) ? s : ALPHA * s;
                }
        // softmax over n
        float invs[2][4];
#pragma unroll
        for (int mt = 0; mt < 2; ++mt)
#pragma unroll
            for (int r = 0; r < 4; ++r) {
                float m2 = fmaxf(acc[mt][0][r], acc[mt][1][r]);
                m2 = fmaxf(m2, __shfl_xor(m2, 1));
                m2 = fmaxf(m2, __shfl_xor(m2, 2));
                m2 = fmaxf(m2, __shfl_xor(m2, 4));
                m2 = fmaxf(m2, __shfl_xor(m2, 8));
                float e0 = __expf(acc[mt][0][r] - m2);
                float e1 = __expf(acc[mt][1][r] - m2);
                acc[mt][0][r] = e0; acc[mt][1][r] = e1;
                float sm = e0 + e1;
                sm += __shfl_xor(sm, 1);
                sm += __shfl_xor(sm, 2);
                sm += __shfl_xor(sm, 4);
                sm += __shfl_xor(sm, 8);
                invs[mt][r] = 1.f / sm;
            }
        unsigned* ATB = (unsigned*)(lds + it * IT) + HLO + half * 544;
#pragma unroll
        for (int mt = 0; mt < 2; ++mt)
#pragma unroll
            for (int rr = 0; rr < 2; ++rr) {
                int md = 8 * mt + 2 * q + rr;
#pragma unroll
                for (int nt = 0; nt < 2; ++nt) {
                    float a0 = acc[mt][nt][rr * 2]     * invs[mt][rr * 2];
                    float a1 = acc[mt][nt][rr * 2 + 1] * invs[mt][rr * 2 + 1];
                    ATB[md * 34 + nt * 16 + m16] = cvtpk_bf16(a0, a1);
                }
            }
    }
    __syncthreads();

    // ---- phase 9+10: (att2 @ h2) via MFMA, D[pos][n] -> bn2 -> pool -> relu -> p2f
    // A = h2 hi+lo, B = att2 HI only: HA*bh + LA*bh.
    {
        const int wave = tid >> 6, lane = tid & 63;
        const int it = wave >> 1, half = wave & 1;
        const int m16 = lane & 15, q = lane >> 4;
        const unsigned short* U = (const unsigned short*)(lds + it * IT);
        const unsigned* ATB = (const unsigned*)(lds + it * IT) + HLO + half * 544;

        // A-frag: A[pos=m16][k=m] = h2[ch][pos]; h2bf hi us base 0, lo us base 792
        int kd = m16 >> 1, par = m16 & 1;
        union { unsigned u[4]; short8 v; } HA, LA;
#pragma unroll
        for (int i = 0; i < 4; ++i) {
            int ch = half * 32 + q * 8 + 2 * i;
            unsigned h0 = U[kd * 132 + ch * 2 + par];
            unsigned h1u = U[kd * 132 + (ch + 1) * 2 + par];
            unsigned l0 = U[792 + kd * 132 + ch * 2 + par];
            unsigned l1 = U[792 + kd * 132 + (ch + 1) * 2 + par];
            HA.u[i] = h0 | (h1u << 16);
            LA.u[i] = l0 | (l1 << 16);
        }
        // B-frags: attb dwords (md = q*4+i, n = nt*16+m16)
        short8 bh[2];
#pragma unroll
        for (int nt = 0; nt < 2; ++nt) {
            union { unsigned u[4]; short8 v; } H;
#pragma unroll
            for (int i = 0; i < 4; ++i)
                H.u[i] = ATB[(q * 4 + i) * 34 + nt * 16 + m16];
            bh[nt] = H.v;
        }
        v4f zz = {0.f, 0.f, 0.f, 0.f};
        v4f acc[2]; acc[0] = zz; acc[1] = zz;
#pragma unroll
        for (int nt = 0; nt < 2; ++nt) {
            acc[nt] = __builtin_amdgcn_mfma_f32_16x16x32_bf16(HA.v, bh[nt], acc[nt], 0, 0, 0);
            acc[nt] = __builtin_amdgcn_mfma_f32_16x16x32_bf16(LA.v, bh[nt], acc[nt], 0, 0, 0);
        }

        __syncthreads();   // all h2bf reads done before p2f overwrites [0,384)

        // epilogue: D[pos=q*4+r][n=nt*16+m16]
        if (q < 3) {
#pragma unroll
            for (int nt = 0; nt < 2; ++nt) {
                int n = nt * 16 + m16;
                float inv = cst[64 + n], sh = cst[96 + n];
#pragma unroll
                for (int rr = 0; rr < 2; ++rr) {
                    int j = q * 2 + rr;
                    float v0 = acc[nt][rr * 2] * inv + sh;
                    float v1 = acc[nt][rr * 2 + 1] * inv + sh;
                    lds[it * IT + n * 12 + half * 6 + j] =
                        fmaxf(fmaxf(v0, v1), 0.f);
                }
            }
        }
    }
    __syncthreads();

    // ---- phase 11: linear 384 -> 13, both items; float4 dot ----
    if (tid < 208) {
        int s8 = tid & 7;
        int rest = tid >> 3;
        int it = (rest >= 13) ? 1 : 0;
        int o = rest - it * 13;
        const float4* wv4 = (const float4*)(lw + o * 384 + s8 * 48);
        const float4* fv4 = (const float4*)&lds[it * IT + s8 * 48];
        float s = 0.f;
#pragma unroll
        for (int i = 0; i < 12; ++i) {
            float4 w4 = wv4[i];
            float4 f4 = fv4[i];
            s += f4.x * w4.x + f4.y * w4.y + f4.z * w4.z + f4.w * w4.w;
        }
        s += __shfl_down(s, 4, 8);
        s += __shfl_down(s, 2, 8);
        s += __shfl_down(s, 1, 8);
        if (s8 == 0) out[(size_t)(b0 + it) * 13 + o] = s + lb[o];
    }
}

extern "C" void kernel_launch(void* const* d_in, const int* in_sizes, int n_in,
                              void* d_out, int out_size, void* d_ws, size_t ws_size,
                              hipStream_t stream) {
    const float* x   = (const float*)d_in[0];
    const float* w1  = (const float*)d_in[1];
    const float* b1  = (const float*)d_in[2];
    const float* g1  = (const float*)d_in[3];
    const float* be1 = (const float*)d_in[4];
    const float* mu1 = (const float*)d_in[5];
    const float* va1 = (const float*)d_in[6];
    const float* w2  = (const float*)d_in[7];
    const float* b2  = (const float*)d_in[8];
    const float* g2  = (const float*)d_in[9];
    const float* be2 = (const float*)d_in[10];
    const float* mu2 = (const float*)d_in[11];
    const float* va2 = (const float*)d_in[12];
    const float* lw  = (const float*)d_in[13];
    const float* lb  = (const float*)d_in[14];
    float* out = (float*)d_out;
    unsigned short* ws16 = (unsigned short*)d_ws;

    // pack conv1 (kw-split) + conv2 weights into MFMA B-fragments, 64 KB in d_ws
    prep_kernel<<<8, 256, 0, stream>>>(w1, w2, ws16);

    int B = in_sizes[0] / 1250;  // 16384
    gcn_kernel<<<B / 2, 256, 0, stream>>>(x, w1, b1, g1, be1, mu1, va1,
                                          w2, b2, g2, be2, mu2, va2, lw, lb,
                                          ws16, out);
}

// Round 10
// 256.617 us; speedup vs baseline: 1.1118x; 1.1118x over previous
//
#include <hip/hip_runtime.h>
#include <math.h>

#define ALPHA 0.2f
#define BN_EPS 1e-5f

typedef __attribute__((ext_vector_type(8))) short short8;
typedef __attribute__((ext_vector_type(4))) float v4f;

// ---- bf16 bit helpers (RNE) ----
__device__ __forceinline__ unsigned short f2bf_rne(float f) {
    union { float f; unsigned u; } x; x.f = f;
    unsigned r = x.u + 0x7FFFu + ((x.u >> 16) & 1u);
    return (unsigned short)(r >> 16);
}
__device__ __forceinline__ float bf2f(unsigned short h) {
    union { float f; unsigned u; } x; x.u = ((unsigned)h) << 16;
    return x.f;
}
// packed f32x2 -> bf16x2 (a0 -> low16). Rounding mode of HW cvt_pk is
// irrelevant for hi/lo pairs: lo is computed against the actual hi.
__device__ __forceinline__ unsigned cvtpk_bf16(float a0, float a1) {
    unsigned r;
    asm("v_cvt_pk_bf16_f32 %0, %1, %2" : "=v"(r) : "v"(a0), "v"(a1));
    return r;
}
__device__ __forceinline__ void hilo_pair(float a0, float a1, unsigned& hp, unsigned& lp) {
    hp = cvtpk_bf16(a0, a1);
    union { unsigned u; float f; } c0, c1;
    c0.u = hp << 16; c1.u = hp & 0xFFFF0000u;
    lp = cvtpk_bf16(a0 - c0.f, a1 - c1.f);
}

// ======== prep kernel: pack conv1 + conv2 weights as MFMA B-fragments ========
// conv1 (kw-split, 11 GEMMs of K=25 pad 32 over k=ic*5+kh): slot
//   s = (kw*2+nt)*64+lane, elem j <-> B_kw[k=(lane>>4)*8+j][oc=nt*16+(lane&15)]
//   = w1[oc*275 + k*11 + kw], zero for k>=25.
//   hi at ws16[0..11264), lo at ws16[11264..22528).
// conv2 (kw-split, 5 GEMMs of K=32=ic): slot s2 = ((kw*2+nt)*64+lane):
//   elem j <-> B_kw[ic=(lane>>4)*8+j][oc=nt*16+(lane&15)] = w2[oc][ic][kw].
//   hi at ws16[22528..27648), lo at ws16[27648..32768).  Total 64 KB.
__global__ __launch_bounds__(256) void prep_kernel(const float* __restrict__ w1,
                                                   const float* __restrict__ w2,
                                                   unsigned short* __restrict__ ws16) {
    int s = blockIdx.x * 256 + threadIdx.x;
    if (s < 1408) {
        int lane = s & 63;
        int ktnt = s >> 6;           // 0..21 = kw*2+nt
        int kw = ktnt >> 1;
        int nt = ktnt & 1;
        int oc = nt * 16 + (lane & 15);
        int quad = lane >> 4;
        for (int j = 0; j < 8; ++j) {
            int k = quad * 8 + j;    // ic*5+kh, pad >=25 zero
            float w = (k < 25) ? w1[oc * 275 + k * 11 + kw] : 0.f;
            unsigned short h = f2bf_rne(w);
            ws16[s * 8 + j] = h;
            ws16[11264 + s * 8 + j] = f2bf_rne(w - bf2f(h));
        }
    } else if (s < 2048) {
        int s2 = s - 1408;
        int lane = s2 & 63;
        int ktnt = s2 >> 6;          // 0..9 = kw*2+nt
        int kw = ktnt >> 1;
        int nt = ktnt & 1;
        int oc = nt * 16 + (lane & 15);
        int quad = lane >> 4;
        for (int j = 0; j < 8; ++j) {
            int ic = quad * 8 + j;
            float w = w2[oc * 160 + ic * 5 + kw];
            unsigned short h = f2bf_rne(w);
            ws16[22528 + s2 * 8 + j] = h;
            ws16[27648 + s2 * 8 + j] = f2bf_rne(w - bf2f(h));
        }
    }
}

// ======== main kernel ========
// Per-item LDS map (dwords, stride IT=2264), regions overlap by lifetime:
//  [0,858)    : hbf-HI (dw kd*66+ch, kd=pos>>1 0..12)  ph1epi..ph4+5-reads;
//               pt [0,832)  ph4+5epi..ph6-reads (barrier inside ph4+5);
//               h2bf hi [0,396)+lo [396,792)  ph6epi..ph9+10-reads (barrier in ph6);
//               p2f f32 [0,384)  ph9+10epi..ph11 (barrier inside ph9+10)
//  [858,1716) : hbf-LO  ph1epi..ph2-MFMA-reads only (barrier inside ph2)
//  [858,1946) : attb bf16 att B-frags, HI ONLY (att-lo term dropped; see ph4+5
//               note): dw half*544 + md*34 + n (md=m>>1 0..15, n 0..31).
//               layer1: ph2epi..ph4+5-reads; layer2: ph7epi..ph9+10-reads
//  [860,2260) : xkT bf16 x^T pair-packed halo'd: [half][w'=0..34][20dw rows]
//               ph0..ph1-MFMAs (barrier inside ph1 before hbf epi)
// cst @4528 [4][32]. Total 4656 dw = 18624 B.
// NOTE: launch_bounds (256,6): the (256,8) variant forced a 64-reg cap -> the
// compiler spilled to scratch (R9: WRITE_SIZE 1MB->91MB, FETCH +40MB, dur
// 147->179). Bound 6 gives an 85-reg budget (R6/R7 compiled at 40-48, no
// spills); if the allocator lands <=64 regs we still reach 8 blocks/CU by LDS.
#define IT 2264
#define HLO 858
#define XKT 860
#define CSTO 4528
#define LDS_TOTAL (4528 + 128)

__global__ __launch_bounds__(256, 6) void gcn_kernel(
    const float* __restrict__ x,
    const float* __restrict__ w1, const float* __restrict__ b1,
    const float* __restrict__ g1, const float* __restrict__ be1,
    const float* __restrict__ mu1, const float* __restrict__ va1,
    const float* __restrict__ w2, const float* __restrict__ b2,
    const float* __restrict__ g2, const float* __restrict__ be2,
    const float* __restrict__ mu2, const float* __restrict__ va2,
    const float* __restrict__ lw, const float* __restrict__ lb,
    const unsigned short* __restrict__ ws16,
    float* __restrict__ out)
{
    __shared__ __align__(16) float lds[LDS_TOTAL];
    float* cst = lds + CSTO;

    const int tid = threadIdx.x;
    const int b0  = blockIdx.x * 2;

    // ---- phase 0: row-based load -> xkT (bf16, transposed, pair-packed, halo) ----
    // xkT row w' holds x[w=(w'-5) mod 25] at us slot k=ic*5+kh; row stride 40 us.
    // main w'=w+5; left halo w'=w-20 (w>=20); right halo w'=w+30 (w<=4).
    if (tid < 250) {
        int rowid = tid / 5;             // (it, k): 50 source rows of 50 floats
        int s = tid - rowid * 5;         // fifth-of-row: w50 in [s*10, s*10+10)
        int it = (rowid >= 25) ? 1 : 0;
        int k = rowid - it * 25;
        const float2* src = (const float2*)(x + (size_t)b0 * 1250) + it * 625 + k * 25 + s * 5;
        unsigned short* XU = (unsigned short*)(lds + it * IT + XKT);
#pragma unroll
        for (int e = 0; e < 5; ++e) {
            float2 v = src[e];
            int w50 = s * 10 + 2 * e;
            {
                int half = (w50 >= 25) ? 1 : 0;
                int w = w50 - half * 25;
                unsigned short u = f2bf_rne(v.x);
                int a = half * 1400 + (w + 5) * 40 + k;
                XU[a] = u;
                if (w >= 20) XU[a - 1000] = u;
                if (w <= 4)  XU[a + 1000] = u;
            }
            {
                int w51 = w50 + 1;
                int half = (w51 >= 25) ? 1 : 0;
                int w = w51 - half * 25;
                unsigned short u = f2bf_rne(v.y);
                int a = half * 1400 + (w + 5) * 40 + k;
                XU[a] = u;
                if (w >= 20) XU[a - 1000] = u;
                if (w <= 4)  XU[a + 1000] = u;
            }
        }
    }
    // zero pads: k=25 ushort + kd 13..15 dwords, all 140 (it,half,w') rows
    if (tid < 140) {
        int it = (tid >= 70) ? 1 : 0;
        int r2 = tid - it * 70;
        int half = (r2 >= 35) ? 1 : 0;
        int w3 = r2 - half * 35;
        int a = half * 1400 + w3 * 40;   // even
        unsigned short* XU = (unsigned short*)(lds + it * IT + XKT);
        XU[a + 25] = 0;
        unsigned* XD = (unsigned*)XU;
        XD[(a >> 1) + 13] = 0;
        XD[(a >> 1) + 14] = 0;
        XD[(a >> 1) + 15] = 0;
    }
    if (tid < 64) {
        int oc = tid & 31;
        if (tid < 32) {
            float inv = g1[oc] * rsqrtf(va1[oc] + BN_EPS);
            cst[oc]      = inv;
            cst[32 + oc] = be1[oc] - mu1[oc] * inv;
        } else {
            float inv = g2[oc] * rsqrtf(va2[oc] + BN_EPS);
            cst[64 + oc] = inv;
            cst[96 + oc] = be2[oc] - mu2[oc] * inv;
        }
    }
    __syncthreads();

    // ---- phase 1: conv1 as 11 kw-split MFMA GEMMs (K=25 pad 32), A=1 b128/tile ----
    // M remap: mg = half*32 + pos (junk rows pos>=25 clamp to 24, discarded in epi).
    {
        const int wave = tid >> 6, lane = tid & 63;
        const int it = wave >> 1;
        const int Mtb = (wave & 1) * 2;
        const int quad = lane >> 4, m16 = lane & 15;
        const unsigned* XK = (const unsigned*)(lds + it * IT + XKT);

        int ab[2];
#pragma unroll
        for (int mt = 0; mt < 2; ++mt) {
            int mg = (Mtb + mt) * 16 + m16;
            int half = mg >> 5, pos = mg & 31;
            pos = (pos > 24) ? 24 : pos;
            ab[mt] = half * 700 + pos * 20 + quad * 4;
        }

        v4f zz = {0.f, 0.f, 0.f, 0.f};
        v4f acc[2][2];
        acc[0][0] = zz; acc[0][1] = zz; acc[1][0] = zz; acc[1][1] = zz;

        for (int kw = 0; kw < 11; ++kw) {
            short8 a0 = *(const short8*)(XK + ab[0] + kw * 20);
            short8 a1 = *(const short8*)(XK + ab[1] + kw * 20);
#pragma unroll
            for (int nt = 0; nt < 2; ++nt) {
                const short8* ph = (const short8*)(ws16 + ((kw * 2 + nt) * 64 + lane) * 8);
                const short8* pl = (const short8*)(ws16 + 11264 + ((kw * 2 + nt) * 64 + lane) * 8);
                short8 bh = *ph;
                short8 bl = *pl;
                acc[0][nt] = __builtin_amdgcn_mfma_f32_16x16x32_bf16(a0, bh, acc[0][nt], 0, 0, 0);
                acc[0][nt] = __builtin_amdgcn_mfma_f32_16x16x32_bf16(a0, bl, acc[0][nt], 0, 0, 0);
                acc[1][nt] = __builtin_amdgcn_mfma_f32_16x16x32_bf16(a1, bh, acc[1][nt], 0, 0, 0);
                acc[1][nt] = __builtin_amdgcn_mfma_f32_16x16x32_bf16(a1, bl, acc[1][nt], 0, 0, 0);
            }
        }

        __syncthreads();   // all xkT reads done before hbf-lo epi overwrites [858,1716)

        // epilogue: D rows quad*4+r are mg; in-lane r-pairs = pos-pairs -> one
        // hilo dword per (kd,ch). hi dw kd*66+ch, lo +858. Pair (24,25): odd
        // slot holds junk (finite acc), masked by ph2 / discarded by ph4+5.
        float biasv0 = b1[m16], biasv1 = b1[16 + m16];
        unsigned* HD = (unsigned*)(lds + it * IT);
#pragma unroll
        for (int mt = 0; mt < 2; ++mt) {
#pragma unroll
            for (int rr = 0; rr < 2; ++rr) {
                int mg0 = (Mtb + mt) * 16 + quad * 4 + rr * 2;
                int half = mg0 >> 5, pos0 = mg0 & 31;
                if (pos0 <= 24) {
                    int kd = pos0 >> 1;
#pragma unroll
                    for (int nt = 0; nt < 2; ++nt) {
                        float bias = nt ? biasv1 : biasv0;
                        float v0 = acc[mt][nt][rr * 2] + bias;
                        float v1 = acc[mt][nt][rr * 2 + 1] + bias;
                        unsigned hp, lp;
                        hilo_pair(v0, v1, hp, lp);
                        int ch = half * 32 + nt * 16 + m16;
                        HD[kd * 66 + ch] = hp;
                        HD[858 + kd * 66 + ch] = lp;
                    }
                }
            }
        }
    }
    __syncthreads();

    // ---- phase 2 (fused): layer-1 scores -> leaky -> softmax(in-reg) -> attb ----
    // S[m][n]=<H[m],H[n]> (K=25 pad 32), m=mt*16+q*4+r, n=nt*16+m16.
    // softmax over n = reduce over (nt regs x m16 lanes) via 4-step shfl_xor.
    // attb (HI only): dw HLO + half*544 + md*34 + n (md=m>>1, in-lane r-pairs).
    {
        const int wave = tid >> 6, lane = tid & 63;
        const int it = wave >> 1, half = wave & 1;
        const int m16 = lane & 15, q = lane >> 4;
        const unsigned* D = (const unsigned*)(lds + it * IT);
        short8 fh[2], fl[2];
#pragma unroll
        for (int t = 0; t < 2; ++t) {
            int row = half * 32 + t * 16 + m16;
            union { unsigned u[4]; short8 v; } H, L;
#pragma unroll
            for (int i = 0; i < 4; ++i) {
                int k0 = q * 8 + 2 * i;
                unsigned mh = D[(k0 >> 1) * 66 + row];
                unsigned ml = D[858 + (k0 >> 1) * 66 + row];
                if (k0 == 24) { mh &= 0xFFFFu; ml &= 0xFFFFu; }
                if (k0 > 24)  { mh = 0u; ml = 0u; }
                H.u[i] = mh; L.u[i] = ml;
            }
            fh[t] = H.v; fl[t] = L.v;
        }
        v4f zz = {0.f, 0.f, 0.f, 0.f};
        v4f acc[2][2];
        acc[0][0] = zz; acc[0][1] = zz; acc[1][0] = zz; acc[1][1] = zz;
#pragma unroll
        for (int mt = 0; mt < 2; ++mt)
#pragma unroll
            for (int nt = 0; nt < 2; ++nt) {
                acc[mt][nt] = __builtin_amdgcn_mfma_f32_16x16x32_bf16(fh[mt], fh[nt], acc[mt][nt], 0, 0, 0);
                acc[mt][nt] = __builtin_amdgcn_mfma_f32_16x16x32_bf16(fh[mt], fl[nt], acc[mt][nt], 0, 0, 0);
                acc[mt][nt] = __builtin_amdgcn_mfma_f32_16x16x32_bf16(fl[mt], fh[nt], acc[mt][nt], 0, 0, 0);
            }
        // leaky
#pragma unroll
        for (int mt = 0; mt < 2; ++mt)
#pragma unroll
            for (int nt = 0; nt < 2; ++nt)
#pragma unroll
                for (int r = 0; r < 4; ++r) {
                    float s = acc[mt][nt][r];
                    acc[mt][nt][r] = (s > 0.f) ? s : ALPHA * s;
                }
        // softmax over n (per m = (mt,r)): max + exp + sum + scale
        float invs[2][4];
#pragma unroll
        for (int mt = 0; mt < 2; ++mt)
#pragma unroll
            for (int r = 0; r < 4; ++r) {
                float m2 = fmaxf(acc[mt][0][r], acc[mt][1][r]);
                m2 = fmaxf(m2, __shfl_xor(m2, 1));
                m2 = fmaxf(m2, __shfl_xor(m2, 2));
                m2 = fmaxf(m2, __shfl_xor(m2, 4));
                m2 = fmaxf(m2, __shfl_xor(m2, 8));
                float e0 = __expf(acc[mt][0][r] - m2);
                float e1 = __expf(acc[mt][1][r] - m2);
                acc[mt][0][r] = e0; acc[mt][1][r] = e1;
                float sm = e0 + e1;
                sm += __shfl_xor(sm, 1);
                sm += __shfl_xor(sm, 2);
                sm += __shfl_xor(sm, 4);
                sm += __shfl_xor(sm, 8);
                invs[mt][r] = 1.f / sm;
            }
        __syncthreads();   // all hbf-lo MFMA reads done before attb overwrites
        unsigned* ATB = (unsigned*)(lds + it * IT) + HLO + half * 544;
#pragma unroll
        for (int mt = 0; mt < 2; ++mt)
#pragma unroll
            for (int rr = 0; rr < 2; ++rr) {
                int md = 8 * mt + 2 * q + rr;
#pragma unroll
                for (int nt = 0; nt < 2; ++nt) {
                    float a0 = acc[mt][nt][rr * 2]     * invs[mt][rr * 2];
                    float a1 = acc[mt][nt][rr * 2 + 1] * invs[mt][rr * 2 + 1];
                    ATB[md * 34 + nt * 16 + m16] = cvtpk_bf16(a0, a1);
                }
            }
    }
    __syncthreads();

    // ---- phase 4+5: (att @ h1) via MFMA, D[pos][n] -> bn1 -> pool (in-lane)
    //      -> relu -> pt. A = h1 HI, B = att HI (both lo terms dropped; each is
    //      2^-9-relative, mirrored pair of R5's verified-neutral drop). 1-term.
    {
        const int wave = tid >> 6, lane = tid & 63;
        const int it = wave >> 1, half = wave & 1;
        const int m16 = lane & 15, q = lane >> 4;
        const unsigned short* U = (const unsigned short*)(lds + it * IT);
        const unsigned* ATB = (const unsigned*)(lds + it * IT) + HLO + half * 544;

        // A-frags (hi): A[pos][k=m] = h1[ch=half*32+m][pos]; pos = mt*16 + m16
        short8 ah[2];
#pragma unroll
        for (int mt = 0; mt < 2; ++mt) {
            int pos = mt * 16 + m16;
            int kd = pos >> 1, par = pos & 1;
            union { unsigned u[4]; short8 v; } H;
#pragma unroll
            for (int i = 0; i < 4; ++i) {
                int ch = half * 32 + q * 8 + 2 * i;
                unsigned h0 = U[kd * 132 + ch * 2 + par];
                unsigned h1u = U[kd * 132 + (ch + 1) * 2 + par];
                H.u[i] = h0 | (h1u << 16);
            }
            ah[mt] = H.v;
        }
        // B-frags: attb dwords (md = q*4+i, n = nt*16+m16)
        short8 bh[2];
#pragma unroll
        for (int nt = 0; nt < 2; ++nt) {
            union { unsigned u[4]; short8 v; } H;
#pragma unroll
            for (int i = 0; i < 4; ++i)
                H.u[i] = ATB[(q * 4 + i) * 34 + nt * 16 + m16];
            bh[nt] = H.v;
        }
        v4f zz = {0.f, 0.f, 0.f, 0.f};
        v4f acc[2][2];
        acc[0][0] = zz; acc[0][1] = zz; acc[1][0] = zz; acc[1][1] = zz;
#pragma unroll
        for (int mt = 0; mt < 2; ++mt)
#pragma unroll
            for (int nt = 0; nt < 2; ++nt)
                acc[mt][nt] = __builtin_amdgcn_mfma_f32_16x16x32_bf16(ah[mt], bh[nt], acc[mt][nt], 0, 0, 0);

        __syncthreads();   // all hbf-hi reads done before pt overwrites [0,832)

        // epilogue: pos = mt*16 + q*4 + r (r-pairs pool in-lane); n = nt*16+m16
        unsigned short* PT = (unsigned short*)(lds + it * IT) + half * 832;
#pragma unroll
        for (int mt = 0; mt < 2; ++mt)
#pragma unroll
            for (int nt = 0; nt < 2; ++nt) {
                int n = nt * 16 + m16;
                float inv = cst[n], sh = cst[32 + n];
#pragma unroll
                for (int rr = 0; rr < 2; ++rr) {
                    int pos0 = mt * 16 + q * 4 + rr * 2;
                    if (pos0 < 24) {
                        float v0 = acc[mt][nt][rr * 2] * inv + sh;
                        float v1 = acc[mt][nt][rr * 2 + 1] * inv + sh;
                        float p = fmaxf(fmaxf(v0, v1), 0.f);
                        int j = pos0 >> 1;
                        unsigned short h = f2bf_rne(p);
                        PT[(n >> 1) * 26 + j * 2 + (n & 1)] = h;
                        PT[416 + (n >> 1) * 26 + j * 2 + (n & 1)] = f2bf_rne(p - bf2f(h));
                    }
                }
            }
    }
    __syncthreads();

    // ---- phase 6: conv2 as 5 kw-split MFMA GEMMs (K=32=ic), A from pt ----
    {
        const int wave = tid >> 6, lane = tid & 63;
        const int it = wave >> 1, half = wave & 1;
        const int m16 = lane & 15, q = lane >> 4;
        const unsigned* PTD = (const unsigned*)(lds + it * IT) + half * 416;

        v4f zz = {0.f, 0.f, 0.f, 0.f};
        v4f acc[2]; acc[0] = zz; acc[1] = zz;
#pragma unroll
        for (int kw = 0; kw < 5; ++kw) {
            int owr = m16 + kw - 2;
            if (owr < 0) owr += 12;
            if (owr >= 12) owr -= 12;
            union { unsigned u[4]; short8 v; } H, L;
#pragma unroll
            for (int i = 0; i < 4; ++i) {
                H.u[i] = PTD[(q * 4 + i) * 13 + owr];
                L.u[i] = PTD[208 + (q * 4 + i) * 13 + owr];
            }
#pragma unroll
            for (int nt = 0; nt < 2; ++nt) {
                const short8* ph = (const short8*)(ws16 + 22528 + ((kw * 2 + nt) * 64 + lane) * 8);
                const short8* pl = (const short8*)(ws16 + 27648 + ((kw * 2 + nt) * 64 + lane) * 8);
                short8 wbh = *ph, wbl = *pl;
                acc[nt] = __builtin_amdgcn_mfma_f32_16x16x32_bf16(H.v, wbh, acc[nt], 0, 0, 0);
                acc[nt] = __builtin_amdgcn_mfma_f32_16x16x32_bf16(H.v, wbl, acc[nt], 0, 0, 0);
                acc[nt] = __builtin_amdgcn_mfma_f32_16x16x32_bf16(L.v, wbh, acc[nt], 0, 0, 0);
            }
        }

        __syncthreads();   // all pt reads done before h2bf overwrites [0,792)

        // epilogue: D[ow=q*4+r][oc]; h2bf hi dw kd*66+ch, lo +396 (kd = ow pair)
        if (q < 3) {
            unsigned* H2 = (unsigned*)(lds + it * IT);
#pragma unroll
            for (int nt = 0; nt < 2; ++nt) {
                float bias = b2[nt * 16 + m16];
                int ch = half * 32 + nt * 16 + m16;
#pragma unroll
                for (int rr = 0; rr < 2; ++rr) {
                    float v0 = acc[nt][rr * 2] + bias;
                    float v1 = acc[nt][rr * 2 + 1] + bias;
                    unsigned hp, lp;
                    hilo_pair(v0, v1, hp, lp);
                    H2[(q * 2 + rr) * 66 + ch] = hp;
                    H2[396 + (q * 2 + rr) * 66 + ch] = lp;
                }
            }
        }
    }
    __syncthreads();

    // ---- phase 7 (fused): layer-2 scores -> leaky -> softmax -> attb (HI only) ----
    // S[m][n]=<H2[1-half][m],H2[half][n]>, K=12 pad 32. attb write region
    // [858,1946) disjoint from h2bf reads [0,792) -> no internal barrier.
    {
        const int wave = tid >> 6, lane = tid & 63;
        const int it = wave >> 1, half = wave & 1;
        const int m16 = lane & 15, q = lane >> 4;
        const unsigned* D = (const unsigned*)(lds + it * IT);
        short8 ah[2], al[2], bh[2], bl[2];
#pragma unroll
        for (int t = 0; t < 2; ++t) {
            int rowA = (1 - half) * 32 + t * 16 + m16;
            int rowB = half * 32 + t * 16 + m16;
            union { unsigned u[4]; short8 v; } HA, LA, HB, LB;
#pragma unroll
            for (int i = 0; i < 4; ++i) {
                int k0 = q * 8 + 2 * i;
                unsigned a_h = D[(k0 >> 1) * 66 + rowA];
                unsigned a_l = D[396 + (k0 >> 1) * 66 + rowA];
                unsigned b_h = D[(k0 >> 1) * 66 + rowB];
                unsigned b_l = D[396 + (k0 >> 1) * 66 + rowB];
                if (k0 > 10) { a_h = 0u; a_l = 0u; b_h = 0u; b_l = 0u; }
                HA.u[i] = a_h; LA.u[i] = a_l; HB.u[i] = b_h; LB.u[i] = b_l;
            }
            ah[t] = HA.v; al[t] = LA.v; bh[t] = HB.v; bl[t] = LB.v;
        }
        v4f zz = {0.f, 0.f, 0.f, 0.f};
        v4f acc[2][2];
        acc[0][0] = zz; acc[0][1] = zz; acc[1][0] = zz; acc[1][1] = zz;
#pragma unroll
        for (int mt = 0; mt < 2; ++mt)
#pragma unroll
            for (int nt = 0; nt < 2; ++nt) {
                acc[mt][nt] = __builtin_amdgcn_mfma_f32_16x16x32_bf16(ah[mt], bh[nt], acc[mt][nt], 0, 0, 0);
                acc[mt][nt] = __builtin_amdgcn_mfma_f32_16x16x32_bf16(ah[mt], bl[nt], acc[mt][nt], 0, 0, 0);
                acc[mt][nt] = __builtin_amdgcn_mfma_f32_16x16x32_bf16(al[mt], bh[nt], acc[mt][nt], 0, 0, 0);
            }
        // leaky
#pragma unroll
        for (int mt = 0; mt < 2; ++mt)
#pragma unroll
            for (int nt = 0; nt < 2; ++nt)
#pragma unroll
                for (int r = 0; r < 4; ++r) {
                    float s = acc[mt][nt][r];
                    acc[mt][nt][r] = (s > 0.f) ? s : ALPHA * s;
                }
        // softmax over n
        float invs[2][4];
#pragma unroll
        for (int mt = 0; mt < 2; ++mt)
#pragma unroll
            for (int r = 0; r < 4; ++r) {
                float m2 = fmaxf(acc[mt][0][r], acc[mt][1][r]);
                m2 = fmaxf(m2, __shfl_xor(m2, 1));
                m2 = fmaxf(m2, __shfl_xor(m2, 2));
                m2 = fmaxf(m2, __shfl_xor(m2, 4));
                m2 = fmaxf(m2, __shfl_xor(m2, 8));
                float e0 = __expf(acc[mt][0][r] - m2);
                float e1 = __expf(acc[mt][1][r] - m2);
                acc[mt][0][r] = e0; acc[mt][1][r] = e1;
                float sm = e0 + e1;
                sm += __shfl_xor(sm, 1);
                sm += __shfl_xor(sm, 2);
                sm += __shfl_xor(sm, 4);
                sm += __shfl_xor(sm, 8);
                invs[mt][r] = 1.f / sm;
            }
        unsigned* ATB = (unsigned*)(lds + it * IT) + HLO + half * 544;
#pragma unroll
        for (int mt = 0; mt < 2; ++mt)
#pragma unroll
            for (int rr = 0; rr < 2; ++rr) {
                int md = 8 * mt + 2 * q + rr;
#pragma unroll
                for (int nt = 0; nt < 2; ++nt) {
                    float a0 = acc[mt][nt][rr * 2]     * invs[mt][rr * 2];
                    float a1 = acc[mt][nt][rr * 2 + 1] * invs[mt][rr * 2 + 1];
                    ATB[md * 34 + nt * 16 + m16] = cvtpk_bf16(a0, a1);
                }
            }
    }
    __syncthreads();

    // ---- phase 9+10: (att2 @ h2) via MFMA, D[pos][n] -> bn2 -> pool -> relu -> p2f
    // A = h2 hi+lo, B = att2 HI only: HA*bh + LA*bh.
    {
        const int wave = tid >> 6, lane = tid & 63;
        const int it = wave >> 1, half = wave & 1;
        const int m16 = lane & 15, q = lane >> 4;
        const unsigned short* U = (const unsigned short*)(lds + it * IT);
        const unsigned* ATB = (const unsigned*)(lds + it * IT) + HLO + half * 544;

        // A-frag: A[pos=m16][k=m] = h2[ch][pos]; h2bf hi us base 0, lo us base 792
        int kd = m16 >> 1, par = m16 & 1;
        union { unsigned u[4]; short8 v; } HA, LA;
#pragma unroll
        for (int i = 0; i < 4; ++i) {
            int ch = half * 32 + q * 8 + 2 * i;
            unsigned h0 = U[kd * 132 + ch * 2 + par];
            unsigned h1u = U[kd * 132 + (ch + 1) * 2 + par];
            unsigned l0 = U[792 + kd * 132 + ch * 2 + par];
            unsigned l1 = U[792 + kd * 132 + (ch + 1) * 2 + par];
            HA.u[i] = h0 | (h1u << 16);
            LA.u[i] = l0 | (l1 << 16);
        }
        // B-frags: attb dwords (md = q*4+i, n = nt*16+m16)
        short8 bh[2];
#pragma unroll
        for (int nt = 0; nt < 2; ++nt) {
            union { unsigned u[4]; short8 v; } H;
#pragma unroll
            for (int i = 0; i < 4; ++i)
                H.u[i] = ATB[(q * 4 + i) * 34 + nt * 16 + m16];
            bh[nt] = H.v;
        }
        v4f zz = {0.f, 0.f, 0.f, 0.f};
        v4f acc[2]; acc[0] = zz; acc[1] = zz;
#pragma unroll
        for (int nt = 0; nt < 2; ++nt) {
            acc[nt] = __builtin_amdgcn_mfma_f32_16x16x32_bf16(HA.v, bh[nt], acc[nt], 0, 0, 0);
            acc[nt] = __builtin_amdgcn_mfma_f32_16x16x32_bf16(LA.v, bh[nt], acc[nt], 0, 0, 0);
        }

        __syncthreads();   // all h2bf reads done before p2f overwrites [0,384)

        // epilogue: D[pos=q*4+r][n=nt*16+m16]
        if (q < 3) {
#pragma unroll
            for (int nt = 0; nt < 2; ++nt) {
                int n = nt * 16 + m16;
                float inv = cst[64 + n], sh = cst[96 + n];
#pragma unroll
                for (int rr = 0; rr < 2; ++rr) {
                    int j = q * 2 + rr;
                    float v0 = acc[nt][rr * 2] * inv + sh;
                    float v1 = acc[nt][rr * 2 + 1] * inv + sh;
                    lds[it * IT + n * 12 + half * 6 + j] =
                        fmaxf(fmaxf(v0, v1), 0.f);
                }
            }
        }
    }
    __syncthreads();

    // ---- phase 11: linear 384 -> 13, both items; float4 dot ----
    if (tid < 208) {
        int s8 = tid & 7;
        int rest = tid >> 3;
        int it = (rest >= 13) ? 1 : 0;
        int o = rest - it * 13;
        const float4* wv4 = (const float4*)(lw + o * 384 + s8 * 48);
        const float4* fv4 = (const float4*)&lds[it * IT + s8 * 48];
        float s = 0.f;
#pragma unroll
        for (int i = 0; i < 12; ++i) {
            float4 w4 = wv4[i];
            float4 f4 = fv4[i];
            s += f4.x * w4.x + f4.y * w4.y + f4.z * w4.z + f4.w * w4.w;
        }
        s += __shfl_down(s, 4, 8);
        s += __shfl_down(s, 2, 8);
        s += __shfl_down(s, 1, 8);
        if (s8 == 0) out[(size_t)(b0 + it) * 13 + o] = s + lb[o];
    }
}

extern "C" void kernel_launch(void* const* d_in, const int* in_sizes, int n_in,
                              void* d_out, int out_size, void* d_ws, size_t ws_size,
                              hipStream_t stream) {
    const float* x   = (const float*)d_in[0];
    const float* w1  = (const float*)d_in[1];
    const float* b1  = (const float*)d_in[2];
    const float* g1  = (const float*)d_in[3];
    const float* be1 = (const float*)d_in[4];
    const float* mu1 = (const float*)d_in[5];
    const float* va1 = (const float*)d_in[6];
    const float* w2  = (const float*)d_in[7];
    const float* b2  = (const float*)d_in[8];
    const float* g2  = (const float*)d_in[9];
    const float* be2 = (const float*)d_in[10];
    const float* mu2 = (const float*)d_in[11];
    const float* va2 = (const float*)d_in[12];
    const float* lw  = (const float*)d_in[13];
    const float* lb  = (const float*)d_in[14];
    float* out = (float*)d_out;
    unsigned short* ws16 = (unsigned short*)d_ws;

    // pack conv1 (kw-split) + conv2 weights into MFMA B-fragments, 64 KB in d_ws
    prep_kernel<<<8, 256, 0, stream>>>(w1, w2, ws16);

    int B = in_sizes[0] / 1250;  // 16384
    gcn_kernel<<<B / 2, 256, 0, stream>>>(x, w1, b1, g1, be1, mu1, va1,
                                          w2, b2, g2, be2, mu2, va2, lw, lb,
                                          ws16, out);
}